// Round 10
// baseline (1198.721 us; speedup 1.0000x reference)
//
#include <hip/hip_runtime.h>
#include <hip/hip_bf16.h>

typedef unsigned short u16;

#define BATCH 8
#define CIN 512
#define COUT 512
#define SDIM 512
#define RES 64
#define PIX (RES * RES)          // 4096
#define PPIX 4356                // padded 66x66
#define PANEL_E 139392           // PPIX*32 elems per padded B panel

__device__ __constant__ static const float kAffScale  = 0.04419417382415922f;   // 1/sqrt(512)
__device__ __constant__ static const float kConvScale = 0.014731391274719742f;  // 1/sqrt(512*9)
__device__ __constant__ static const float kGain      = 1.4142135623730951f;    // sqrt(2)

typedef __bf16 bf16x8 __attribute__((ext_vector_type(8)));
typedef float  f32x4  __attribute__((ext_vector_type(4)));

// ---------------------------------------------------------------------------
// Kernel 1: style[b][c] = (w[b] . affine_w[c]) * AFF_SCALE + affine_b[c]
// ---------------------------------------------------------------------------
__global__ void style_k(const float* __restrict__ w, const float* __restrict__ aw,
                        const float* __restrict__ ab, float* __restrict__ style) {
  int tid = blockIdx.x * 256 + threadIdx.x;      // 0..4095
  int b = tid >> 9, c = tid & 511;
  const float* wp = w + b * SDIM;
  const float* ap = aw + c * SDIM;
  float s = 0.0f;
  for (int k = 0; k < SDIM; ++k) s += wp[k] * ap[k];
  style[tid] = s * kAffScale + ab[c];
}

// ---------------------------------------------------------------------------
// Kernel 2: cw2[o][i] = sum_t conv_w[o][i][t]^2
// ---------------------------------------------------------------------------
__global__ void cw2_k(const float* __restrict__ cw, float* __restrict__ cw2) {
  int tid = blockIdx.x * 256 + threadIdx.x;      // o*512+i
  const float* p = cw + tid * 9;
  float s = 0.0f;
  #pragma unroll
  for (int t = 0; t < 9; ++t) { float v = p[t]; s += v * v; }
  cw2[tid] = s;
}

// ---------------------------------------------------------------------------
// Kernel 3: fac[b][o] = CONV_SCALE * rsqrt(CONV_SCALE^2 * sum_i style^2*cw2 + 1e-8)
// ---------------------------------------------------------------------------
__global__ void fac_k(const float* __restrict__ style, const float* __restrict__ cw2,
                      float* __restrict__ fac) {
  int wid  = blockIdx.x * 4 + (threadIdx.x >> 6); // 0..4095
  int lane = threadIdx.x & 63;
  int b = wid >> 9, o = wid & 511;
  const float* st = style + b * CIN;
  const float* c2 = cw2 + o * CIN;
  float s = 0.0f;
  for (int i = lane; i < CIN; i += 64) { float sv = st[i]; s += sv * sv * c2[i]; }
  #pragma unroll
  for (int off = 32; off; off >>= 1) s += __shfl_xor(s, off);
  if (lane == 0) {
    float d = rsqrtf(s * kConvScale * kConvScale + 1e-8f);
    fac[wid] = d * kConvScale;
  }
}

// ---------------------------------------------------------------------------
// Kernel 4: wbt[(tap*16+sl)][o][j] = bf16(conv_w[o][sl*32+j][tap])
// ---------------------------------------------------------------------------
__global__ void wcast_k(const float* __restrict__ cw, u16* __restrict__ wbt) {
  int tid = blockIdx.x * 256 + threadIdx.x;      // o*512 + i
  int o = tid >> 9, i = tid & 511;
  const float* p = cw + tid * 9;
  #pragma unroll
  for (int t = 0; t < 9; ++t) {
    __hip_bfloat16 h = __float2bfloat16(p[t]);
    wbt[((size_t)(t * 16 + (i >> 5)) * 512 + o) * 32 + (i & 31)] = *(u16*)&h;
  }
}

// ---------------------------------------------------------------------------
// Kernel 5a: zero the 1-pixel borders of all 128 padded B panels
// ---------------------------------------------------------------------------
__global__ void bz_k(u16* __restrict__ xst) {
  int idx = blockIdx.x * 256 + threadIdx.x;      // panel*4356 + pix
  if (idx >= 128 * PPIX) return;
  int pan = idx / PPIX, pix = idx - pan * PPIX;
  int h = pix / 66, w = pix - h * 66;
  if (h == 0 || h == 65 || w == 0 || w == 65) {
    u16* p = xst + (size_t)pan * PANEL_E + (size_t)pix * 32;
    int4 z = make_int4(0, 0, 0, 0);
    ((int4*)p)[0] = z; ((int4*)p)[1] = z; ((int4*)p)[2] = z; ((int4*)p)[3] = z;
  }
}

// ---------------------------------------------------------------------------
// Kernel 5b: xst[(b*16+sl)][(h+1)*66+(w+1)][j] = bf16(x[b][sl*32+j][h*64+w]*style)
// ---------------------------------------------------------------------------
__global__ void modx_k(const float* __restrict__ x, const float* __restrict__ style,
                       u16* __restrict__ xst) {
  __shared__ float t[64][65];
  int b  = blockIdx.z;
  int it = blockIdx.y * 64;                      // cin tile base
  int pt = blockIdx.x * 64;                      // pixel tile base
  int tp = threadIdx.x & 63;
  int tr = threadIdx.x >> 6;                     // 0..3
  for (int r = tr; r < 64; r += 4) {
    int i = it + r;
    t[r][tp] = x[(b * CIN + i) * PIX + pt + tp] * style[b * CIN + i];
  }
  __syncthreads();
  int i = it + tp;
  size_t pbase = (size_t)(b * 16 + (i >> 5)) * PANEL_E + (i & 31);
  for (int r = tr; r < 64; r += 4) {
    int pix = pt + r, h = pix >> 6, w = pix & 63;
    __hip_bfloat16 hh = __float2bfloat16(t[tp][r]);
    xst[pbase + (size_t)((h + 1) * 66 + (w + 1)) * 32] = *(u16*)&hh;
  }
}

// ---------------------------------------------------------------------------
// Kernel 6: implicit-GEMM conv, OCCUPANCY-FIRST variant.
// BM=BN=128, 4 waves (2Mx2N), wave out 64x64, grid 1024 = 4 blocks/CU.
// LDS: A-only double buffer [2][2kh][128 rows][32] = 32 KB.
// B: direct global->VGPR (coalesced b128 from padded NHWC-32 panels),
// ping-pong reg sets, issued 1 K-tile ahead. Per K-tile (32 MFMA):
// stA(t+1), issue B(t+1), 8 ds_read, 32 MFMA, vmcnt(8), barrier (1/tile).
// vmcnt(8) drains exactly A(t+1) (FIFO: A4 then B8); B waits auto-inserted.
// cin-block-major K-order (cb 0..7 x tap 0..8), cb-unrolled x2 for parity.
// ---------------------------------------------------------------------------
__launch_bounds__(256, 4)
__global__ void gemm_k(const u16* __restrict__ wbt, const u16* __restrict__ xst,
                       const float* __restrict__ fac, const float* __restrict__ noise,
                       const float* __restrict__ nscale_p, const float* __restrict__ bias,
                       float* __restrict__ y) {
  __shared__ __align__(16) u16 Ab[16384];        // [d][kh*4096 + c*8] = 32 KB

  const int tid = threadIdx.x;
  const int bid = blockIdx.x;                    // 0..1023
  const int swz = (bid & 7) * 128 + (bid >> 3);  // XCD-chunked (1024 % 8 == 0)
  const int mt = swz & 3;                        // cout tile (consecutive swz share B)
  const int nt = swz >> 2;                       // 0..255 pixel tile
  const int b  = nt >> 5;                        // image
  const int hbase = (nt & 31) * 2;               // image row base (2 rows per tile)
  const int pimg  = hbase * 64;                  // pixel base

  const int lane = tid & 63;
  const int wv = tid >> 6;                       // 0..3
  const int wm = wv >> 1, wn = wv & 1;           // 2x2 wave grid
  const int l15 = lane & 15, l4 = lane >> 4;

  // A-read element addresses (per-thread constants), 4 m-fragments
  int aElem[4];
  #pragma unroll
  for (int mi = 0; mi < 4; ++mi) {
    int arow = wm * 64 + mi * 16 + l15;
    aElem[mi] = arow * 32 + ((l4 ^ ((arow >> 1) & 3)) << 3);
  }

  // A staging per-thread constants: chunk c = p*256+tid, row=c>>2, slot=c&3
  const int sgE = ((tid & 3) ^ ((tid >> 3) & 3)) << 3;
  int aoffE[2];
  #pragma unroll
  for (int p = 0; p < 2; ++p)
    aoffE[p] = (mt * 128 + ((p * 256 + tid) >> 2)) * 32 + sgE;

  // B per-lane constant offset (elems) within a padded panel (center pixel)
  const int pB0 = ((hbase + wn + 1) * 66 + l15 + 1) * 32 + l4 * 8;

  // stage both kh-slices of A K-tile (tap,cb) into buffer d
  auto stA = [&](int tap, int cbs, int d) {
    #pragma unroll
    for (int kh = 0; kh < 2; ++kh) {
      const u16* pan = wbt + ((size_t)(tap * 16 + cbs * 2 + kh) << 14);
      #pragma unroll
      for (int p = 0; p < 2; ++p) {
        __builtin_amdgcn_global_load_lds(
            (const __attribute__((address_space(1))) void*)(pan + aoffE[p]),
            (__attribute__((address_space(3))) void*)(&Ab[d * 8192 + kh * 4096 + (p * 256 + tid) * 8]),
            16, 0, 0);
      }
    }
  };

  f32x4 acc[4][4];
  #pragma unroll
  for (int i = 0; i < 4; ++i)
    #pragma unroll
    for (int j = 0; j < 4; ++j) acc[i][j] = (f32x4){0.f, 0.f, 0.f, 0.f};

  bf16x8 q0[8], q1[8];                           // B reg sets: [kh*4 + ni]

#define BISSUE(QS, TAPB, CBB) {                                                \
    _Pragma("unroll") for (int kh = 0; kh < 2; ++kh) {                         \
      const u16* pb_ = xst + (size_t)(b * 16 + (CBB) * 2 + kh) * PANEL_E       \
          + ((((TAPB) / 3) - 1) * 66 + ((TAPB) % 3) - 1) * 32 + pB0;           \
      _Pragma("unroll") for (int ni = 0; ni < 4; ++ni)                         \
        QS[kh * 4 + ni] = *(const bf16x8*)(pb_ + ni * 512);                    \
    }                                                                          \
  }

  // Prologue: A(0) -> buf0 (4 gll), B(0) -> q0 (8 loads); drain A only.
  stA(0, 0, 0);
  BISSUE(q0, 0, 0)
  asm volatile("s_waitcnt vmcnt(8)" ::: "memory");
  __builtin_amdgcn_s_barrier();

  // One K-tile: read buf D, consume QC; stage A(next)->buf D^1, B(next)->QN.
#define KTILE(D, QC, QN, TAPS, CBS) {                                          \
    stA(TAPS, CBS, (D) ^ 1);                                                   \
    BISSUE(QN, TAPS, CBS)                                                      \
    bf16x8 af0[4], af1[4];                                                     \
    _Pragma("unroll") for (int j = 0; j < 4; ++j)                              \
      af0[j] = *(const bf16x8*)&Ab[(D) * 8192 + aElem[j]];                     \
    _Pragma("unroll") for (int j = 0; j < 4; ++j)                              \
      af1[j] = *(const bf16x8*)&Ab[(D) * 8192 + 4096 + aElem[j]];              \
    __builtin_amdgcn_sched_barrier(0);  /* issues above, MFMA below */         \
    __builtin_amdgcn_s_setprio(1);                                             \
    _Pragma("unroll") for (int j = 0; j < 4; ++j)                              \
      _Pragma("unroll") for (int ni = 0; ni < 4; ++ni)                         \
        acc[j][ni] = __builtin_amdgcn_mfma_f32_16x16x32_bf16(af0[j], QC[ni], acc[j][ni], 0, 0, 0); \
    _Pragma("unroll") for (int j = 0; j < 4; ++j)                              \
      _Pragma("unroll") for (int ni = 0; ni < 4; ++ni)                         \
        acc[j][ni] = __builtin_amdgcn_mfma_f32_16x16x32_bf16(af1[j], QC[4 + ni], acc[j][ni], 0, 0, 0); \
    __builtin_amdgcn_s_setprio(0);                                             \
    asm volatile("s_waitcnt vmcnt(8)" ::: "memory");  /* drains A(next) */     \
    __builtin_amdgcn_s_barrier();                                              \
  }

  for (int cb = 0; cb < 8; cb += 2) {
    const int cb1 = cb + 1;
    const int cb2 = (cb + 2) & 7;
    // cb even: global t parity = tap&1 (buf D = tap&1, q parity same)
    KTILE(0, q0, q1, 1, cb)  KTILE(1, q1, q0, 2, cb)  KTILE(0, q0, q1, 3, cb)
    KTILE(1, q1, q0, 4, cb)  KTILE(0, q0, q1, 5, cb)  KTILE(1, q1, q0, 6, cb)
    KTILE(0, q0, q1, 7, cb)  KTILE(1, q1, q0, 8, cb)  KTILE(0, q0, q1, 0, cb1)
    // cb odd: parity flipped
    KTILE(1, q1, q0, 1, cb1) KTILE(0, q0, q1, 2, cb1) KTILE(1, q1, q0, 3, cb1)
    KTILE(0, q0, q1, 4, cb1) KTILE(1, q1, q0, 5, cb1) KTILE(0, q0, q1, 6, cb1)
    KTILE(1, q1, q0, 7, cb1) KTILE(0, q0, q1, 8, cb1) KTILE(1, q1, q0, 0, cb2)
  }
#undef KTILE
#undef BISSUE

  // Epilogue: y = lrelu(acc*fac + noise*nscale + bias) * sqrt(2)
  const float ns = nscale_p[0];
  float nz[4];
  #pragma unroll
  for (int ni = 0; ni < 4; ++ni) {
    int pix = pimg + wn * 64 + ni * 16 + l15;
    nz[ni] = noise[b * PIX + pix] * ns;
  }
  #pragma unroll
  for (int mi = 0; mi < 4; ++mi) {
    int o = mt * 128 + wm * 64 + mi * 16 + l4 * 4;
    f32x4 fv = *(const f32x4*)&fac[b * COUT + o];
    f32x4 bv = *(const f32x4*)&bias[o];
    #pragma unroll
    for (int r = 0; r < 4; ++r) {
      float* yp = y + (size_t)(b * COUT + o + r) * PIX + pimg + wn * 64 + l15;
      #pragma unroll
      for (int ni = 0; ni < 4; ++ni) {
        float v = acc[mi][ni][r] * fv[r] + nz[ni] + bv[r];
        v = (v > 0.0f ? v : 0.2f * v) * kGain;
        yp[ni * 16] = v;
      }
    }
  }
}

// ---------------------------------------------------------------------------
extern "C" void kernel_launch(void* const* d_in, const int* in_sizes, int n_in,
                              void* d_out, int out_size, void* d_ws, size_t ws_size,
                              hipStream_t stream) {
  const float* x      = (const float*)d_in[0];
  const float* w      = (const float*)d_in[1];
  const float* noise  = (const float*)d_in[2];
  const float* aff_w  = (const float*)d_in[3];
  const float* aff_b  = (const float*)d_in[4];
  const float* conv_w = (const float*)d_in[5];
  const float* nscale = (const float*)d_in[6];
  const float* bias   = (const float*)d_in[7];
  float* y = (float*)d_out;

  char* ws = (char*)d_ws;
  float* style = (float*)(ws);                          // 16 KB
  float* fac   = (float*)(ws + 16384);                  // 16 KB
  float* cw2   = (float*)(ws + 32768);                  // 1 MB
  u16*   wbt   = (u16*)(ws + 1081600);                  // 4.5 MB panels
  u16*   xst   = (u16*)(ws + 5800192);                  // 128 padded panels, 35.7 MB

  style_k<<<16, 256, 0, stream>>>(w, aff_w, aff_b, style);
  cw2_k<<<1024, 256, 0, stream>>>(conv_w, cw2);
  fac_k<<<1024, 256, 0, stream>>>(style, cw2, fac);
  wcast_k<<<1024, 256, 0, stream>>>(conv_w, wbt);
  bz_k<<<(128 * PPIX + 255) / 256, 256, 0, stream>>>(xst);
  modx_k<<<dim3(64, 8, 8), 256, 0, stream>>>(x, style, xst);
  gemm_k<<<1024, 256, 0, stream>>>(wbt, xst, fac, noise, nscale, bias, y);
}

// Round 11
// 187.358 us; speedup vs baseline: 6.3980x; 6.3980x over previous
//
#include <hip/hip_runtime.h>
#include <hip/hip_bf16.h>

typedef unsigned short u16;

#define BATCH 8
#define CIN 512
#define COUT 512
#define SDIM 512
#define RES 64
#define PIX (RES * RES)          // 4096
#define PPIX 4356                // padded 66x66
#define PANEL_E 139392           // PPIX*32 elems per padded B panel

__device__ __constant__ static const float kAffScale  = 0.04419417382415922f;   // 1/sqrt(512)
__device__ __constant__ static const float kConvScale = 0.014731391274719742f;  // 1/sqrt(512*9)
__device__ __constant__ static const float kGain      = 1.4142135623730951f;    // sqrt(2)

typedef __bf16 bf16x8 __attribute__((ext_vector_type(8)));
typedef float  f32x4  __attribute__((ext_vector_type(4)));

// ---------------------------------------------------------------------------
// Kernel 1: style[b][c] = (w[b] . affine_w[c]) * AFF_SCALE + affine_b[c]
// ---------------------------------------------------------------------------
__global__ void style_k(const float* __restrict__ w, const float* __restrict__ aw,
                        const float* __restrict__ ab, float* __restrict__ style) {
  int tid = blockIdx.x * 256 + threadIdx.x;      // 0..4095
  int b = tid >> 9, c = tid & 511;
  const float* wp = w + b * SDIM;
  const float* ap = aw + c * SDIM;
  float s = 0.0f;
  for (int k = 0; k < SDIM; ++k) s += wp[k] * ap[k];
  style[tid] = s * kAffScale + ab[c];
}

// ---------------------------------------------------------------------------
// Kernel 2: cw2[o][i] = sum_t conv_w[o][i][t]^2
// ---------------------------------------------------------------------------
__global__ void cw2_k(const float* __restrict__ cw, float* __restrict__ cw2) {
  int tid = blockIdx.x * 256 + threadIdx.x;      // o*512+i
  const float* p = cw + tid * 9;
  float s = 0.0f;
  #pragma unroll
  for (int t = 0; t < 9; ++t) { float v = p[t]; s += v * v; }
  cw2[tid] = s;
}

// ---------------------------------------------------------------------------
// Kernel 3: fac[b][o] = CONV_SCALE * rsqrt(CONV_SCALE^2 * sum_i style^2*cw2 + 1e-8)
// ---------------------------------------------------------------------------
__global__ void fac_k(const float* __restrict__ style, const float* __restrict__ cw2,
                      float* __restrict__ fac) {
  int wid  = blockIdx.x * 4 + (threadIdx.x >> 6); // 0..4095
  int lane = threadIdx.x & 63;
  int b = wid >> 9, o = wid & 511;
  const float* st = style + b * CIN;
  const float* c2 = cw2 + o * CIN;
  float s = 0.0f;
  for (int i = lane; i < CIN; i += 64) { float sv = st[i]; s += sv * sv * c2[i]; }
  #pragma unroll
  for (int off = 32; off; off >>= 1) s += __shfl_xor(s, off);
  if (lane == 0) {
    float d = rsqrtf(s * kConvScale * kConvScale + 1e-8f);
    fac[wid] = d * kConvScale;
  }
}

// ---------------------------------------------------------------------------
// Kernel 4: wbt[(tap*16+sl)][o][j] = bf16(conv_w[o][sl*32+j][tap])
// ---------------------------------------------------------------------------
__global__ void wcast_k(const float* __restrict__ cw, u16* __restrict__ wbt) {
  int tid = blockIdx.x * 256 + threadIdx.x;      // o*512 + i
  int o = tid >> 9, i = tid & 511;
  const float* p = cw + tid * 9;
  #pragma unroll
  for (int t = 0; t < 9; ++t) {
    __hip_bfloat16 h = __float2bfloat16(p[t]);
    wbt[((size_t)(t * 16 + (i >> 5)) * 512 + o) * 32 + (i & 31)] = *(u16*)&h;
  }
}

// ---------------------------------------------------------------------------
// Kernel 5a: zero the 1-pixel borders of all 128 padded B panels
// ---------------------------------------------------------------------------
__global__ void bz_k(u16* __restrict__ xst) {
  int idx = blockIdx.x * 256 + threadIdx.x;      // panel*4356 + pix
  if (idx >= 128 * PPIX) return;
  int pan = idx / PPIX, pix = idx - pan * PPIX;
  int h = pix / 66, w = pix - h * 66;
  if (h == 0 || h == 65 || w == 0 || w == 65) {
    u16* p = xst + (size_t)pan * PANEL_E + (size_t)pix * 32;
    int4 z = make_int4(0, 0, 0, 0);
    ((int4*)p)[0] = z; ((int4*)p)[1] = z; ((int4*)p)[2] = z; ((int4*)p)[3] = z;
  }
}

// ---------------------------------------------------------------------------
// Kernel 5b: xst[(b*16+sl)][(h+1)*66+(w+1)][j] = bf16(x[b][sl*32+j][h*64+w]*style)
// ---------------------------------------------------------------------------
__global__ void modx_k(const float* __restrict__ x, const float* __restrict__ style,
                       u16* __restrict__ xst) {
  __shared__ float t[64][65];
  int b  = blockIdx.z;
  int it = blockIdx.y * 64;                      // cin tile base
  int pt = blockIdx.x * 64;                      // pixel tile base
  int tp = threadIdx.x & 63;
  int tr = threadIdx.x >> 6;                     // 0..3
  for (int r = tr; r < 64; r += 4) {
    int i = it + r;
    t[r][tp] = x[(b * CIN + i) * PIX + pt + tp] * style[b * CIN + i];
  }
  __syncthreads();
  int i = it + tp;
  size_t pbase = (size_t)(b * 16 + (i >> 5)) * PANEL_E + (i & 31);
  for (int r = tr; r < 64; r += 4) {
    int pix = pt + r, h = pix >> 6, w = pix & 63;
    __hip_bfloat16 hh = __float2bfloat16(t[tp][r]);
    xst[pbase + (size_t)((h + 1) * 66 + (w + 1)) * 32] = *(u16*)&hh;
  }
}

// ---------------------------------------------------------------------------
// Kernel 6: implicit-GEMM conv, TLP-FIRST variant (m97 discipline).
// BM=256 (cout), BN=128 (pixels), 256 threads = 4 waves (2Mx2N),
// wave out 128x64. Grid 512 = 2 independent blocks/CU (the lever).
// A: single 32 KB LDS buffer via global_load_lds (swizzled slots).
// B: direct global->VGPR from padded NHWC-32 panels (bit-identical to LDS
// path, rides the VMEM pipe in parallel with LDS).
// Per K-tile: stage A (8 gll) | issue B (8 b128) | __syncthreads (drain) |
// 16 ds_read + 64 MFMA | __syncthreads. No inline asm; sibling block on the
// CU hides the drains (m114 co-scheduling).
// cb-major K-order; XCD chunk = 1 cout-panel + 2 images (L2 ~3.4 MB).
// ---------------------------------------------------------------------------
__launch_bounds__(256, 2)
__global__ void gemm_k(const u16* __restrict__ wbt, const u16* __restrict__ xst,
                       const float* __restrict__ fac, const float* __restrict__ noise,
                       const float* __restrict__ nscale_p, const float* __restrict__ bias,
                       float* __restrict__ y) {
  __shared__ __align__(16) u16 Ab[16384];        // [kh][256 rows][32 elems] = 32 KB

  const int tid = threadIdx.x;
  const int bid = blockIdx.x;                    // 0..511
  const int swz = (bid & 7) * 64 + (bid >> 3);   // XCD-chunked (512 = 8*64)
  const int mt = swz >> 8;                       // 0..1   cout tile (uniform per XCD chunk)
  const int nt = swz & 255;                      // 0..255 pixel tile
  const int b  = nt >> 5;                        // image
  const int hbase = (nt & 31) * 2;               // image row base (2 rows per tile)
  const int pimg  = hbase * 64;                  // pixel base

  const int lane = tid & 63;
  const int wv = tid >> 6;                       // 0..3
  const int wm = wv >> 1, wn = wv & 1;           // 2x2 wave grid
  const int l15 = lane & 15, l4 = lane >> 4;

  // A-read element addresses (per-thread constants), 8 m-fragments (128 rows)
  int aElem[8];
  #pragma unroll
  for (int mi = 0; mi < 8; ++mi) {
    int arow = wm * 128 + mi * 16 + l15;
    aElem[mi] = arow * 32 + ((l4 ^ ((arow >> 1) & 3)) << 3);
  }

  // A staging constants: per kh 1024 chunks, 4 per thread: c = p*256+tid
  const int sgE = ((tid & 3) ^ ((tid >> 3) & 3)) << 3;
  int aoffE[4];
  #pragma unroll
  for (int p = 0; p < 4; ++p)
    aoffE[p] = (mt * 256 + ((p * 256 + tid) >> 2)) * 32 + sgE;

  // B per-lane constant offset within a padded panel (center pixel of my row)
  const int pB0 = ((hbase + wn + 1) * 66 + l15 + 1) * 32 + l4 * 8;

  f32x4 acc[8][4];
  #pragma unroll
  for (int i = 0; i < 8; ++i)
    #pragma unroll
    for (int j = 0; j < 4; ++j) acc[i][j] = (f32x4){0.f, 0.f, 0.f, 0.f};

  for (int cb = 0; cb < 8; ++cb) {
    for (int ty = 0; ty < 3; ++ty) {
      for (int tx = 0; tx < 3; ++tx) {
        const int tap = ty * 3 + tx;
        // ---- stage A(tap, cb) into the single LDS buffer (8 gll/thread) ----
        #pragma unroll
        for (int kh = 0; kh < 2; ++kh) {
          const u16* pan = wbt + ((size_t)(tap * 16 + cb * 2 + kh) << 14);
          #pragma unroll
          for (int p = 0; p < 4; ++p) {
            __builtin_amdgcn_global_load_lds(
                (const __attribute__((address_space(1))) void*)(pan + aoffE[p]),
                (__attribute__((address_space(3))) void*)(&Ab[kh * 8192 + (p * 256 + tid) * 8]),
                16, 0, 0);
          }
        }
        // ---- issue B(tap, cb) direct to VGPRs (8 coalesced b128/lane) ----
        bf16x8 bfr[8];                           // [kh*4 + ni]
        #pragma unroll
        for (int kh = 0; kh < 2; ++kh) {
          const u16* pb = xst + (size_t)(b * 16 + cb * 2 + kh) * PANEL_E
              + ((ty - 1) * 66 + tx - 1) * 32 + pB0;
          #pragma unroll
          for (int ni = 0; ni < 4; ++ni)
            bfr[kh * 4 + ni] = *(const bf16x8*)(pb + ni * 512);
        }
        __syncthreads();                         // drain DMA + loads; publish A
        // ---- compute: per kh, 8 A-frag reads + 32 MFMA ----
        #pragma unroll
        for (int kh = 0; kh < 2; ++kh) {
          bf16x8 af[8];
          #pragma unroll
          for (int mi = 0; mi < 8; ++mi)
            af[mi] = *(const bf16x8*)&Ab[kh * 8192 + aElem[mi]];
          #pragma unroll
          for (int mi = 0; mi < 8; ++mi)
            #pragma unroll
            for (int ni = 0; ni < 4; ++ni)
              acc[mi][ni] = __builtin_amdgcn_mfma_f32_16x16x32_bf16(
                  af[mi], bfr[kh * 4 + ni], acc[mi][ni], 0, 0, 0);
        }
        __syncthreads();                         // all reads done before next stage
      }
    }
  }

  // Epilogue: y = lrelu(acc*fac + noise*nscale + bias) * sqrt(2)
  const float ns = nscale_p[0];
  float nz[4];
  #pragma unroll
  for (int ni = 0; ni < 4; ++ni) {
    int pix = pimg + wn * 64 + ni * 16 + l15;
    nz[ni] = noise[b * PIX + pix] * ns;
  }
  #pragma unroll
  for (int mi = 0; mi < 8; ++mi) {
    int o = mt * 256 + wm * 128 + mi * 16 + l4 * 4;
    f32x4 fv = *(const f32x4*)&fac[b * COUT + o];
    f32x4 bv = *(const f32x4*)&bias[o];
    #pragma unroll
    for (int r = 0; r < 4; ++r) {
      float* yp = y + (size_t)(b * COUT + o + r) * PIX + pimg + wn * 64 + l15;
      #pragma unroll
      for (int ni = 0; ni < 4; ++ni) {
        float v = acc[mi][ni][r] * fv[r] + nz[ni] + bv[r];
        v = (v > 0.0f ? v : 0.2f * v) * kGain;
        yp[ni * 16] = v;
      }
    }
  }
}

// ---------------------------------------------------------------------------
extern "C" void kernel_launch(void* const* d_in, const int* in_sizes, int n_in,
                              void* d_out, int out_size, void* d_ws, size_t ws_size,
                              hipStream_t stream) {
  const float* x      = (const float*)d_in[0];
  const float* w      = (const float*)d_in[1];
  const float* noise  = (const float*)d_in[2];
  const float* aff_w  = (const float*)d_in[3];
  const float* aff_b  = (const float*)d_in[4];
  const float* conv_w = (const float*)d_in[5];
  const float* nscale = (const float*)d_in[6];
  const float* bias   = (const float*)d_in[7];
  float* y = (float*)d_out;

  char* ws = (char*)d_ws;
  float* style = (float*)(ws);                          // 16 KB
  float* fac   = (float*)(ws + 16384);                  // 16 KB
  float* cw2   = (float*)(ws + 32768);                  // 1 MB
  u16*   wbt   = (u16*)(ws + 1081600);                  // 4.5 MB panels
  u16*   xst   = (u16*)(ws + 5800192);                  // 128 padded panels, 35.7 MB

  style_k<<<16, 256, 0, stream>>>(w, aff_w, aff_b, style);
  cw2_k<<<1024, 256, 0, stream>>>(conv_w, cw2);
  fac_k<<<1024, 256, 0, stream>>>(style, cw2, fac);
  wcast_k<<<1024, 256, 0, stream>>>(conv_w, wbt);
  bz_k<<<(128 * PPIX + 255) / 256, 256, 0, stream>>>(xst);
  modx_k<<<dim3(64, 8, 8), 256, 0, stream>>>(x, style, xst);
  gemm_k<<<512, 256, 0, stream>>>(wbt, xst, fac, noise, nscale, bias, y);
}